// Round 2
// baseline (109.566 us; speedup 1.0000x reference)
//
#include <hip/hip_runtime.h>
#include <hip/hip_bf16.h>

#define N_TOK 4096        // B*T = 32*128
#define EMB_D 64
#define NEG_K 512
#define LOGITS_W 513      // 1 + NEG_K

// ---------------------------------------------------------------------------
// Kernel 1: projection x = embeds @ W + b, and zero the loss accumulator.
// ---------------------------------------------------------------------------
__global__ __launch_bounds__(256) void proj_kernel(
    const float* __restrict__ embeds,
    const float* __restrict__ W,
    const float* __restrict__ b,
    float* __restrict__ x,
    float* __restrict__ loss)
{
    __shared__ float Ws[EMB_D][EMB_D];   // 16 KB
    __shared__ float Es[4][EMB_D];
    const int tid = threadIdx.x;
    const int n0 = blockIdx.x * 4;

    for (int i = tid; i < EMB_D * EMB_D; i += 256)
        Ws[i >> 6][i & 63] = W[i];
    for (int i = tid; i < 4 * EMB_D; i += 256)
        Es[i >> 6][i & 63] = embeds[(size_t)n0 * EMB_D + i];
    __syncthreads();

    const int nl = tid >> 6;    // local row 0..3
    const int e  = tid & 63;    // output dim
    float acc = b[e];
    #pragma unroll
    for (int d = 0; d < EMB_D; ++d)
        acc += Es[nl][d] * Ws[d][e];
    x[(size_t)(n0 + nl) * EMB_D + e] = acc;

    if (blockIdx.x == 0 && tid == 0) loss[0] = 0.0f;
}

// ---------------------------------------------------------------------------
// Kernel 2: per-token scoring. 512 threads/block, one token per block.
// 16 lanes cooperatively gather ONE table row (16 x float4 = 256 B
// contiguous) -> 4 lanes share each 64B line -> coalesced gather.
// ---------------------------------------------------------------------------
__global__ __launch_bounds__(512) void score_kernel(
    const float* __restrict__ x,        // [N,64]
    const int*   __restrict__ labels,   // [N]
    const int*   __restrict__ neg,      // [N,512]
    const float* __restrict__ table,    // [1e6,64]
    float* __restrict__ logits,         // [N,513]
    float* __restrict__ loss)           // [1]
{
    const int n   = blockIdx.x;
    const int tid = threadIdx.x;
    const int g   = tid >> 4;   // group 0..31 (one row per group per iter)
    const int l   = tid & 15;   // lane within group

    __shared__ float xs[EMB_D];
    __shared__ int   nidx[NEG_K];
    __shared__ float sc[LOGITS_W];
    __shared__ float red[8];
    __shared__ float Ms;

    nidx[tid] = neg[(size_t)n * NEG_K + tid];
    if (tid < EMB_D) xs[tid] = x[(size_t)n * EMB_D + tid];
    __syncthreads();

    const float4 xr = ((const float4*)xs)[l];   // loop-invariant fragment

    // ---- positive score: group 0 (lanes 0..15) ----
    if (tid < 16) {
        const int pidx = labels[n];
        const float4 r = ((const float4*)(table + (size_t)pidx * EMB_D))[l];
        float p = r.x * xr.x + r.y * xr.y + r.z * xr.z + r.w * xr.w;
        #pragma unroll
        for (int o = 8; o > 0; o >>= 1) p += __shfl_xor(p, o, 16);
        if (tid == 0) sc[0] = p;
    }

    // ---- negatives: 32 groups x 16 iterations = 512 rows ----
    #pragma unroll
    for (int i = 0; i < 16; ++i) {
        const int k   = i * 32 + g;
        const int idx = nidx[k];
        const float4 r = ((const float4*)(table + (size_t)idx * EMB_D))[l];
        float p = r.x * xr.x + r.y * xr.y + r.z * xr.z + r.w * xr.w;
        #pragma unroll
        for (int o = 8; o > 0; o >>= 1) p += __shfl_xor(p, o, 16);
        if (l == 0) sc[1 + k] = p;
    }
    __syncthreads();

    // ---- block max over all 513 scores ----
    const float v = sc[1 + tid];          // tid 0..511 -> negatives
    float m = (tid == 0) ? fmaxf(v, sc[0]) : v;
    #pragma unroll
    for (int o = 32; o > 0; o >>= 1) m = fmaxf(m, __shfl_xor(m, o));
    const int wave = tid >> 6;
    if ((tid & 63) == 0) red[wave] = m;
    __syncthreads();
    if (tid == 0) {
        float mm = red[0];
        #pragma unroll
        for (int w = 1; w < 8; ++w) mm = fmaxf(mm, red[w]);
        Ms = mm;
    }
    __syncthreads();
    const float M = Ms;

    // ---- block sum of exp ----
    float e = expf(v - M);
    #pragma unroll
    for (int o = 32; o > 0; o >>= 1) e += __shfl_xor(e, o);
    __syncthreads();             // red[] reads from max pass complete
    if ((tid & 63) == 0) red[wave] = e;
    __syncthreads();

    // ---- coalesced logits write: 513 floats ----
    logits[(size_t)n * LOGITS_W + tid] = sc[tid];
    if (tid == 0) {
        logits[(size_t)n * LOGITS_W + 512] = sc[512];
        const float pos = sc[0];
        float s = expf(pos - M);
        #pragma unroll
        for (int w = 0; w < 8; ++w) s += red[w];
        const float lse = M + logf(s);
        atomicAdd(loss, (lse - pos) * (1.0f / (float)N_TOK));
    }
}

extern "C" void kernel_launch(void* const* d_in, const int* in_sizes, int n_in,
                              void* d_out, int out_size, void* d_ws, size_t ws_size,
                              hipStream_t stream) {
    const float* embeds = (const float*)d_in[0];   // [32,128,64]
    const int*   labels = (const int*)d_in[1];     // [4096]
    const int*   neg    = (const int*)d_in[2];     // [4096,512]
    const float* proj_w = (const float*)d_in[3];   // [64,64]
    const float* proj_b = (const float*)d_in[4];   // [64]
    const float* table  = (const float*)d_in[5];   // [1e6,64]

    float* logits = (float*)d_out;                             // [4096,513]
    float* loss   = (float*)d_out + (size_t)N_TOK * LOGITS_W;  // [1]
    float* x      = (float*)d_ws;                              // [4096,64]

    proj_kernel<<<N_TOK / 4, 256, 0, stream>>>(embeds, proj_w, proj_b, x, loss);
    score_kernel<<<N_TOK, 512, 0, stream>>>(x, labels, neg, table, logits, loss);
}